// Round 2
// baseline (920.437 us; speedup 1.0000x reference)
//
#include <hip/hip_runtime.h>
#include <hip/hip_bf16.h>
#include <stdint.h>

// PatchMixerBlock: patchify(16x16) -> LN -> Linear(768->1536)+GELU(exact)
//                  -> Linear(1536->768) -> fold + residual.  All fp32 I/O.
// Strategy: bf16x3 split GEMMs (AhiBhi + AhiBlo + AloBhi) on 32x32x16 MFMA.
// R1: switched 16x16x32 -> 32x32x16 MFMA (m06: +15%/FLOP, half the instrs).

#define TOK   36864     // 64 * 576 tokens
#define PS    768       // patch vector size = 3*16*16
#define HID   1536
#define NPB   576       // patches per image (24*24)
#define WPDIM 24

typedef __attribute__((ext_vector_type(8)))  short bf16x8_t;
typedef __attribute__((ext_vector_type(16))) float floatx16_t;

__device__ __forceinline__ ushort f2bf(float f) {
    union { __hip_bfloat16 h; ushort u; } cv;
    cv.h = __float2bfloat16(f);
    return cv.u;
}
__device__ __forceinline__ float bf2f(ushort u) {
    union { ushort u; __hip_bfloat16 h; } cv;
    cv.u = u;
    return __bfloat162float(cv.h);
}

__device__ __forceinline__ void gload16(const ushort* g, ushort* l) {
    __builtin_amdgcn_global_load_lds((__attribute__((address_space(1))) const void*)g,
                                     (__attribute__((address_space(3))) void*)l, 16, 0, 0);
}

// ---------------------------------------------------------------------------
// Weight transpose + bf16 hi/lo split: in [K][N] fp32  ->  out [N][K] bf16 x2
// ---------------------------------------------------------------------------
__global__ __launch_bounds__(256)
void wsplit_transpose(const float* __restrict__ in, int K, int N,
                      ushort* __restrict__ outHi, ushort* __restrict__ outLo)
{
    __shared__ float tile[32][33];
    const int n0 = blockIdx.x * 32, k0 = blockIdx.y * 32;
    const int tx = threadIdx.x & 31, ty = threadIdx.x >> 5;  // ty 0..7
#pragma unroll
    for (int i = 0; i < 4; ++i) {
        const int kl = ty + i * 8;
        tile[kl][tx] = in[(size_t)(k0 + kl) * N + n0 + tx];
    }
    __syncthreads();
#pragma unroll
    for (int i = 0; i < 4; ++i) {
        const int nl = ty + i * 8;
        const float v = tile[tx][nl];
        const ushort hi = f2bf(v);
        const ushort lo = f2bf(v - bf2f(hi));
        const size_t o = (size_t)(n0 + nl) * K + k0 + tx;
        outHi[o] = hi;
        outLo[o] = lo;
    }
}

// ---------------------------------------------------------------------------
// Patchify + LayerNorm -> Y hi/lo bf16 [TOK][PS]. One wave per token.
// ---------------------------------------------------------------------------
__global__ __launch_bounds__(256)
void patch_ln_kernel(const float* __restrict__ x, const float* __restrict__ lnw,
                     const float* __restrict__ lnb,
                     ushort* __restrict__ Yhi, ushort* __restrict__ Ylo)
{
    const int wave = threadIdx.x >> 6, lane = threadIdx.x & 63;
    const int t = blockIdx.x * 4 + wave;
    const int b  = t / NPB;
    const int l  = t - b * NPB;
    const int hp = l / WPDIM;
    const int wp = l - hp * WPDIM;
    const float* xb = x + (size_t)b * 3 * 384 * 384;

    float v[12];
    float s = 0.f, ss = 0.f;
#pragma unroll
    for (int w = 0; w < 3; ++w) {
        const int p  = w * 256 + lane * 4;
        const int c  = p >> 8, ph = (p >> 4) & 15, pw = p & 15;
        const float4 f = *(const float4*)(xb + (size_t)(c * 384 + hp * 16 + ph) * 384 + wp * 16 + pw);
        v[w*4+0] = f.x; v[w*4+1] = f.y; v[w*4+2] = f.z; v[w*4+3] = f.w;
        s  += f.x + f.y + f.z + f.w;
        ss += f.x*f.x + f.y*f.y + f.z*f.z + f.w*f.w;
    }
#pragma unroll
    for (int off = 32; off > 0; off >>= 1) {
        s  += __shfl_xor(s,  off);
        ss += __shfl_xor(ss, off);
    }
    const float mu = s * (1.f / 768.f);
    const float rs = rsqrtf(fmaxf(ss * (1.f / 768.f) - mu * mu, 0.f) + 1e-5f);

#pragma unroll
    for (int w = 0; w < 3; ++w) {
        const int p = w * 256 + lane * 4;
        const float4 gw = *(const float4*)(lnw + p);
        const float4 gb = *(const float4*)(lnb + p);
        union { ushort u[4]; uint2 q; } hi, lo;
        float yv;
        yv = (v[w*4+0] - mu) * rs * gw.x + gb.x; hi.u[0] = f2bf(yv); lo.u[0] = f2bf(yv - bf2f(hi.u[0]));
        yv = (v[w*4+1] - mu) * rs * gw.y + gb.y; hi.u[1] = f2bf(yv); lo.u[1] = f2bf(yv - bf2f(hi.u[1]));
        yv = (v[w*4+2] - mu) * rs * gw.z + gb.z; hi.u[2] = f2bf(yv); lo.u[2] = f2bf(yv - bf2f(hi.u[2]));
        yv = (v[w*4+3] - mu) * rs * gw.w + gb.w; hi.u[3] = f2bf(yv); lo.u[3] = f2bf(yv - bf2f(hi.u[3]));
        *(uint2*)(Yhi + (size_t)t * PS + p) = hi.q;
        *(uint2*)(Ylo + (size_t)t * PS + p) = lo.q;
    }
}

// ---------------------------------------------------------------------------
// bf16x3 GEMM: C[M,N] = A[M,K] * Bt[N,K]^T (+bias). 128x128 tile, 4 waves,
// BK=32, double-buffered LDS via global_load_lds, XOR-swizzled 16B chunks
// (pre-swizzled global source + swizzled ds_read slot — both-sides rule #21).
// MFMA: v_mfma_f32_32x32x16_bf16, per wave 2x2 tiles of 32x32, 24 MFMA/K-tile.
// DO_GELU=1: epilogue GELU + split -> OutHi/OutLo bf16.
// DO_GELU=0: epilogue fold to [B,C,H,W] + residual add -> out fp32.
// ---------------------------------------------------------------------------
__device__ __forceinline__ void stage_ktile(
    const ushort* __restrict__ Ahi, const ushort* __restrict__ Alo,
    const ushort* __restrict__ Bhi, const ushort* __restrict__ Blo,
    ushort* lA_hi, ushort* lA_lo, ushort* lB_hi, ushort* lB_lo,
    int brow, int bcol, int K, int k0, int wave, int lane)
{
    const int r = lane >> 2;                                   // row within 16-row slab
    const int chunk = ((lane & 3) ^ ((lane >> 3) & 3)) * 8;    // swizzled src chunk (elems)
#pragma unroll
    for (int j = 0; j < 2; ++j) {
        const int row = j * 64 + wave * 16 + r;
        const size_t ga = (size_t)(brow + row) * K + k0 + chunk;
        const size_t gb = (size_t)(bcol + row) * K + k0 + chunk;
        const int lofs = (j * 64 + wave * 16) * 32;            // wave-uniform LDS base (elems)
        gload16(Ahi + ga, lA_hi + lofs);
        gload16(Alo + ga, lA_lo + lofs);
        gload16(Bhi + gb, lB_hi + lofs);
        gload16(Blo + gb, lB_lo + lofs);
    }
}

template<int DO_GELU>
__global__ __launch_bounds__(256, 2)
void gemm_bf16x3(const ushort* __restrict__ Ahi, const ushort* __restrict__ Alo,
                 const ushort* __restrict__ Bhi, const ushort* __restrict__ Blo,
                 const float* __restrict__ bias,
                 int M, int N, int K,
                 ushort* __restrict__ OutHi, ushort* __restrict__ OutLo,
                 const float* __restrict__ xres, float* __restrict__ out)
{
    __shared__ __align__(16) ushort lds[2][4][128 * 32];   // 64 KiB -> 2 blocks/CU
    const int tid  = threadIdx.x;
    const int wave = tid >> 6, lane = tid & 63;
    const int brow = blockIdx.y * 128, bcol = blockIdx.x * 128;
    const int wr = (wave >> 1) * 64, wc = (wave & 1) * 64;

    floatx16_t acc[2][2];
#pragma unroll
    for (int i = 0; i < 2; ++i)
#pragma unroll
        for (int j = 0; j < 2; ++j)
#pragma unroll
            for (int e = 0; e < 16; ++e) acc[i][j][e] = 0.f;

    stage_ktile(Ahi, Alo, Bhi, Blo, lds[0][0], lds[0][1], lds[0][2], lds[0][3],
                brow, bcol, K, 0, wave, lane);
    __syncthreads();

    // 32x32x16 fragment addressing: lane&31 = row(A)/col(B), lane>>5 = k-half.
    const int fr = lane & 31;
    const int kh = lane >> 5;
    const int sw = (fr >> 1) & 3;        // == ((fr&15)>>1)&3 — matches staging swizzle

    const int KT = K >> 5;
    int buf = 0;
    for (int kt = 0; kt < KT; ++kt) {
        if (kt + 1 < KT)
            stage_ktile(Ahi, Alo, Bhi, Blo,
                        lds[buf ^ 1][0], lds[buf ^ 1][1], lds[buf ^ 1][2], lds[buf ^ 1][3],
                        brow, bcol, K, (kt + 1) * 32, wave, lane);

        bf16x8_t ah[2][2], al[2][2], bh[2][2], bl[2][2];   // [tile][k-slice]
#pragma unroll
        for (int mi = 0; mi < 2; ++mi)
#pragma unroll
            for (int s = 0; s < 2; ++s) {
                const int c = (s * 2 + kh) ^ sw;
                const int off = (wr + mi * 32 + fr) * 32 + c * 8;
                ah[mi][s] = *(const bf16x8_t*)&lds[buf][0][off];
                al[mi][s] = *(const bf16x8_t*)&lds[buf][1][off];
            }
#pragma unroll
        for (int ni = 0; ni < 2; ++ni)
#pragma unroll
            for (int s = 0; s < 2; ++s) {
                const int c = (s * 2 + kh) ^ sw;
                const int off = (wc + ni * 32 + fr) * 32 + c * 8;
                bh[ni][s] = *(const bf16x8_t*)&lds[buf][2][off];
                bl[ni][s] = *(const bf16x8_t*)&lds[buf][3][off];
            }
#pragma unroll
        for (int mi = 0; mi < 2; ++mi)
#pragma unroll
            for (int ni = 0; ni < 2; ++ni)
#pragma unroll
                for (int s = 0; s < 2; ++s) {
                    acc[mi][ni] = __builtin_amdgcn_mfma_f32_32x32x16_bf16(ah[mi][s], bh[ni][s], acc[mi][ni], 0, 0, 0);
                    acc[mi][ni] = __builtin_amdgcn_mfma_f32_32x32x16_bf16(ah[mi][s], bl[ni][s], acc[mi][ni], 0, 0, 0);
                    acc[mi][ni] = __builtin_amdgcn_mfma_f32_32x32x16_bf16(al[mi][s], bh[ni][s], acc[mi][ni], 0, 0, 0);
                }
        __syncthreads();
        buf ^= 1;
    }

    // epilogue: 32x32 C/D layout (m74/m101): col = lane&31,
    //           row = (reg&3) + 8*(reg>>2) + 4*(lane>>5)
    const int ocol  = lane & 31;
    const int orow4 = (lane >> 5) * 4;
#pragma unroll
    for (int mi = 0; mi < 2; ++mi) {
#pragma unroll
        for (int ni = 0; ni < 2; ++ni) {
            const int col = bcol + wc + ni * 32 + ocol;
            const float bv = bias[col];
#pragma unroll
            for (int reg = 0; reg < 16; ++reg) {
                const int row = brow + wr + mi * 32 + orow4 + (reg & 3) + 8 * (reg >> 2);
                float v = acc[mi][ni][reg] + bv;
                if (DO_GELU) {
                    v = 0.5f * v * (1.0f + erff(v * 0.70710678118654752f));
                    const ushort hi = f2bf(v);
                    const ushort lo = f2bf(v - bf2f(hi));
                    const size_t o = (size_t)row * N + col;
                    OutHi[o] = hi;
                    OutLo[o] = lo;
                } else {
                    const int t  = row;
                    const int b  = t / NPB;
                    const int l  = t - b * NPB;
                    const int hp = l / WPDIM;
                    const int wp = l - hp * WPDIM;
                    const int c  = col >> 8, ph = (col >> 4) & 15, pw = col & 15;
                    const size_t idx = ((size_t)(b * 3 + c) * 384 + hp * 16 + ph) * 384 + wp * 16 + pw;
                    out[idx] = xres[idx] + v;
                }
            }
        }
    }
}

// ---------------------------------------------------------------------------
extern "C" void kernel_launch(void* const* d_in, const int* in_sizes, int n_in,
                              void* d_out, int out_size, void* d_ws, size_t ws_size,
                              hipStream_t stream)
{
    const float* x   = (const float*)d_in[0];
    const float* lnw = (const float*)d_in[1];
    const float* lnb = (const float*)d_in[2];
    const float* w1  = (const float*)d_in[3];
    const float* b1  = (const float*)d_in[4];
    const float* w2  = (const float*)d_in[5];
    const float* b2  = (const float*)d_in[6];
    float* out = (float*)d_out;

    char* ws = (char*)d_ws;
    size_t o = 0;
    ushort* Yhi  = (ushort*)(ws + o); o += (size_t)TOK * PS * 2;
    ushort* Ylo  = (ushort*)(ws + o); o += (size_t)TOK * PS * 2;
    ushort* W1h  = (ushort*)(ws + o); o += (size_t)PS * HID * 2;
    ushort* W1l  = (ushort*)(ws + o); o += (size_t)PS * HID * 2;
    ushort* W2h  = (ushort*)(ws + o); o += (size_t)HID * PS * 2;
    ushort* W2l  = (ushort*)(ws + o); o += (size_t)HID * PS * 2;
    ushort* Hh   = (ushort*)(ws + o); o += (size_t)TOK * HID * 2;
    ushort* Hl   = (ushort*)(ws + o); o += (size_t)TOK * HID * 2;

    // w1 [PS][HID] -> [HID][PS] hi/lo ; w2 [HID][PS] -> [PS][HID] hi/lo
    wsplit_transpose<<<dim3(HID / 32, PS / 32), 256, 0, stream>>>(w1, PS, HID, W1h, W1l);
    wsplit_transpose<<<dim3(PS / 32, HID / 32), 256, 0, stream>>>(w2, HID, PS, W2h, W2l);

    patch_ln_kernel<<<TOK / 4, 256, 0, stream>>>(x, lnw, lnb, Yhi, Ylo);

    // GEMM1: [TOK,PS] x [PS,HID] -> H [TOK,HID], +b1, GELU, split
    gemm_bf16x3<1><<<dim3(HID / 128, TOK / 128), 256, 0, stream>>>(
        Yhi, Ylo, W1h, W1l, b1, TOK, HID, PS, Hh, Hl, nullptr, nullptr);

    // GEMM2: [TOK,HID] x [HID,PS] -> fold + residual -> out
    gemm_bf16x3<0><<<dim3(PS / 128, TOK / 128), 256, 0, stream>>>(
        Hh, Hl, W2h, W2l, b2, TOK, PS, HID, nullptr, nullptr, x, out);
}

// Round 3
// 888.713 us; speedup vs baseline: 1.0357x; 1.0357x over previous
//
#include <hip/hip_runtime.h>
#include <hip/hip_bf16.h>
#include <stdint.h>

// PatchMixerBlock: patchify(16x16) -> LN -> Linear(768->1536)+GELU(exact)
//                  -> Linear(1536->768) -> fold + residual.  All fp32 I/O.
// bf16x3 split GEMMs (AhiBhi + AhiBlo + AloBhi) on 32x32x16 MFMA.
// R2: 256x256 tile / 8 waves (per-wave 128x64), hi|lo packed in K (128B LDS
//     rows, 8x16B slots), row&7 XOR slot swizzle (both-sides), raw s_barrier
//     + counted vmcnt(8), setprio around MFMA, XCD-chunked block swizzle.

#define TOK   36864
#define PS    768
#define HID   1536
#define NPB   576
#define WPDIM 24

typedef __attribute__((ext_vector_type(8)))  short bf16x8_t;
typedef __attribute__((ext_vector_type(16))) float floatx16_t;

__device__ __forceinline__ ushort f2bf(float f) {
    union { __hip_bfloat16 h; ushort u; } cv;
    cv.h = __float2bfloat16(f);
    return cv.u;
}
__device__ __forceinline__ float bf2f(ushort u) {
    union { ushort u; __hip_bfloat16 h; } cv;
    cv.u = u;
    return __bfloat162float(cv.h);
}

__device__ __forceinline__ void gload16(const ushort* g, ushort* l) {
    __builtin_amdgcn_global_load_lds((__attribute__((address_space(1))) const void*)g,
                                     (__attribute__((address_space(3))) void*)l, 16, 0, 0);
}

#define SCB() __builtin_amdgcn_sched_barrier(0)

// ---------------------------------------------------------------------------
// Weight transpose + bf16 hi/lo split: in [K][N] fp32  ->  out [N][K] bf16 x2
// ---------------------------------------------------------------------------
__global__ __launch_bounds__(256)
void wsplit_transpose(const float* __restrict__ in, int K, int N,
                      ushort* __restrict__ outHi, ushort* __restrict__ outLo)
{
    __shared__ float tile[32][33];
    const int n0 = blockIdx.x * 32, k0 = blockIdx.y * 32;
    const int tx = threadIdx.x & 31, ty = threadIdx.x >> 5;
#pragma unroll
    for (int i = 0; i < 4; ++i) {
        const int kl = ty + i * 8;
        tile[kl][tx] = in[(size_t)(k0 + kl) * N + n0 + tx];
    }
    __syncthreads();
#pragma unroll
    for (int i = 0; i < 4; ++i) {
        const int nl = ty + i * 8;
        const float v = tile[tx][nl];
        const ushort hi = f2bf(v);
        const ushort lo = f2bf(v - bf2f(hi));
        const size_t o = (size_t)(n0 + nl) * K + k0 + tx;
        outHi[o] = hi;
        outLo[o] = lo;
    }
}

// ---------------------------------------------------------------------------
// Patchify + LayerNorm -> Y hi/lo bf16 [TOK][PS]. One wave per token.
// ---------------------------------------------------------------------------
__global__ __launch_bounds__(256)
void patch_ln_kernel(const float* __restrict__ x, const float* __restrict__ lnw,
                     const float* __restrict__ lnb,
                     ushort* __restrict__ Yhi, ushort* __restrict__ Ylo)
{
    const int wave = threadIdx.x >> 6, lane = threadIdx.x & 63;
    const int t = blockIdx.x * 4 + wave;
    const int b  = t / NPB;
    const int l  = t - b * NPB;
    const int hp = l / WPDIM;
    const int wp = l - hp * WPDIM;
    const float* xb = x + (size_t)b * 3 * 384 * 384;

    float v[12];
    float s = 0.f, ss = 0.f;
#pragma unroll
    for (int w = 0; w < 3; ++w) {
        const int p  = w * 256 + lane * 4;
        const int c  = p >> 8, ph = (p >> 4) & 15, pw = p & 15;
        const float4 f = *(const float4*)(xb + (size_t)(c * 384 + hp * 16 + ph) * 384 + wp * 16 + pw);
        v[w*4+0] = f.x; v[w*4+1] = f.y; v[w*4+2] = f.z; v[w*4+3] = f.w;
        s  += f.x + f.y + f.z + f.w;
        ss += f.x*f.x + f.y*f.y + f.z*f.z + f.w*f.w;
    }
#pragma unroll
    for (int off = 32; off > 0; off >>= 1) {
        s  += __shfl_xor(s,  off);
        ss += __shfl_xor(ss, off);
    }
    const float mu = s * (1.f / 768.f);
    const float rs = rsqrtf(fmaxf(ss * (1.f / 768.f) - mu * mu, 0.f) + 1e-5f);

#pragma unroll
    for (int w = 0; w < 3; ++w) {
        const int p = w * 256 + lane * 4;
        const float4 gw = *(const float4*)(lnw + p);
        const float4 gb = *(const float4*)(lnb + p);
        union { ushort u[4]; uint2 q; } hi, lo;
        float yv;
        yv = (v[w*4+0] - mu) * rs * gw.x + gb.x; hi.u[0] = f2bf(yv); lo.u[0] = f2bf(yv - bf2f(hi.u[0]));
        yv = (v[w*4+1] - mu) * rs * gw.y + gb.y; hi.u[1] = f2bf(yv); lo.u[1] = f2bf(yv - bf2f(hi.u[1]));
        yv = (v[w*4+2] - mu) * rs * gw.z + gb.z; hi.u[2] = f2bf(yv); lo.u[2] = f2bf(yv - bf2f(hi.u[2]));
        yv = (v[w*4+3] - mu) * rs * gw.w + gb.w; hi.u[3] = f2bf(yv); lo.u[3] = f2bf(yv - bf2f(hi.u[3]));
        *(uint2*)(Yhi + (size_t)t * PS + p) = hi.q;
        *(uint2*)(Ylo + (size_t)t * PS + p) = lo.q;
    }
}

// ---------------------------------------------------------------------------
// bf16x3 GEMM, 256x256 tile, 8 waves (2Mx4N -> per-wave 128x64), BK=32 real K
// per step stored as 64 bf16/row (octets 0..3 = hi k0..31, 4..7 = lo k0..31).
// LDS row = 128 B = 8 slots of 16 B; slot s of row r holds global octet s^(r&7)
// (staged via pre-swizzled per-lane global source; LDS dest stays linear).
// Double-buffered 2x(32+32) KiB = 128 KiB. Raw s_barrier + counted vmcnt(8).
// ---------------------------------------------------------------------------
template<int DO_GELU>
__global__ __launch_bounds__(512, 1)
void gemm_bf16x3_8p(const ushort* __restrict__ Ahi, const ushort* __restrict__ Alo,
                    const ushort* __restrict__ Bhi, const ushort* __restrict__ Blo,
                    const float* __restrict__ bias,
                    int M, int N, int K, int nbx,
                    ushort* __restrict__ OutHi, ushort* __restrict__ OutLo,
                    const float* __restrict__ xres, float* __restrict__ out)
{
    __shared__ __align__(16) ushort lds[2][2][256 * 64];   // [dbuf][A,B] 128 KiB
    const int tid  = threadIdx.x;
    const int wave = tid >> 6, lane = tid & 63;

    // XCD-chunked swizzle (nwg % 8 == 0 for both GEMMs)
    const int nwg = gridDim.x;
    const int wg  = (blockIdx.x & 7) * (nwg >> 3) + (blockIdx.x >> 3);
    const int bx  = wg % nbx, by = wg / nbx;
    const int brow = by * 256, bcol = bx * 256;

    const int wrm = wave >> 2;            // 0..1  (M offset wrm*128)
    const int wrn = wave & 3;             // 0..3  (N offset wrn*64)

    // staging geometry: wave stages rows [wave*32, wave*32+32) of both panels
    const int rb = wave * 32;
    const int lr = lane >> 3, sl = lane & 7;
    const int g  = sl ^ lr;               // global octet this lane fetches
    const int go = (g & 3) * 8;           // element offset within hi/lo window
    const ushort* PA = (g < 4) ? Ahi : Alo;
    const ushort* PB = (g < 4) ? Bhi : Blo;

    floatx16_t acc[4][2];
#pragma unroll
    for (int mi = 0; mi < 4; ++mi)
#pragma unroll
        for (int ni = 0; ni < 2; ++ni)
#pragma unroll
            for (int e = 0; e < 16; ++e) acc[mi][ni][e] = 0.f;

    const int KT = K >> 5;

    // prologue: stage tile 0 into buf 0
#pragma unroll
    for (int i = 0; i < 4; ++i) {
        const int r = rb + i * 8 + lr;
        gload16(PA + (size_t)(brow + r) * K + go, (ushort*)&lds[0][0][(rb + i * 8) * 64]);
        gload16(PB + (size_t)(bcol + r) * K + go, (ushort*)&lds[0][1][(rb + i * 8) * 64]);
    }
    SCB();

    const int fr = lane & 31;             // fragment row (A) / col (B)
    const int kh = lane >> 5;             // k-octet within 16-wide slice
    const int sx = fr & 7;                // slot swizzle selector

    for (int t = 0; t < KT; ++t) {
        const int cur = t & 1;
        if (t + 1 < KT) {
            const int k0 = (t + 1) * 32;
#pragma unroll
            for (int i = 0; i < 4; ++i) {
                const int r = rb + i * 8 + lr;
                gload16(PA + (size_t)(brow + r) * K + k0 + go, (ushort*)&lds[cur ^ 1][0][(rb + i * 8) * 64]);
                gload16(PB + (size_t)(bcol + r) * K + k0 + go, (ushort*)&lds[cur ^ 1][1][(rb + i * 8) * 64]);
            }
            SCB();
            asm volatile("s_waitcnt vmcnt(8)" ::: "memory");   // tile t landed, t+1 in flight
        } else {
            SCB();
            asm volatile("s_waitcnt vmcnt(0)" ::: "memory");   // final tile: full drain
        }
        SCB();
        __builtin_amdgcn_s_barrier();
        SCB();

#pragma unroll
        for (int s = 0; s < 2; ++s) {
            bf16x8_t ah[4], al[4], bh[2], bl[2];
            const int sh  = (s * 2 + kh) ^ sx;       // hi slot
            const int slo = (4 + s * 2 + kh) ^ sx;   // lo slot
#pragma unroll
            for (int mi = 0; mi < 4; ++mi) {
                const int R = wrm * 128 + mi * 32 + fr;
                ah[mi] = *(const bf16x8_t*)&lds[cur][0][R * 64 + sh * 8];
                al[mi] = *(const bf16x8_t*)&lds[cur][0][R * 64 + slo * 8];
            }
#pragma unroll
            for (int ni = 0; ni < 2; ++ni) {
                const int R = wrn * 64 + ni * 32 + fr;
                bh[ni] = *(const bf16x8_t*)&lds[cur][1][R * 64 + sh * 8];
                bl[ni] = *(const bf16x8_t*)&lds[cur][1][R * 64 + slo * 8];
            }
            __builtin_amdgcn_s_setprio(1);
#pragma unroll
            for (int mi = 0; mi < 4; ++mi)
#pragma unroll
                for (int ni = 0; ni < 2; ++ni) {
                    acc[mi][ni] = __builtin_amdgcn_mfma_f32_32x32x16_bf16(ah[mi], bh[ni], acc[mi][ni], 0, 0, 0);
                    acc[mi][ni] = __builtin_amdgcn_mfma_f32_32x32x16_bf16(ah[mi], bl[ni], acc[mi][ni], 0, 0, 0);
                    acc[mi][ni] = __builtin_amdgcn_mfma_f32_32x32x16_bf16(al[mi], bh[ni], acc[mi][ni], 0, 0, 0);
                }
            __builtin_amdgcn_s_setprio(0);
        }
        asm volatile("s_waitcnt lgkmcnt(0)" ::: "memory");     // reads serviced before others re-stage
        SCB();
        __builtin_amdgcn_s_barrier();
        SCB();
    }

    // epilogue: C/D layout col = lane&31, row = (reg&3)+8*(reg>>2)+4*(lane>>5)
    const int ocol = lane & 31;
    const int or4  = kh * 4;
#pragma unroll
    for (int mi = 0; mi < 4; ++mi) {
#pragma unroll
        for (int ni = 0; ni < 2; ++ni) {
            const int col = bcol + wrn * 64 + ni * 32 + ocol;
            const float bv = bias[col];
#pragma unroll
            for (int reg = 0; reg < 16; ++reg) {
                const int row = brow + wrm * 128 + mi * 32 + or4 + (reg & 3) + 8 * (reg >> 2);
                float v = acc[mi][ni][reg] + bv;
                if (DO_GELU) {
                    v = 0.5f * v * (1.0f + erff(v * 0.70710678118654752f));
                    const ushort hi = f2bf(v);
                    const ushort lo = f2bf(v - bf2f(hi));
                    const size_t o = (size_t)row * N + col;
                    OutHi[o] = hi;
                    OutLo[o] = lo;
                } else {
                    const int tk = row;
                    const int b  = tk / NPB;
                    const int l  = tk - b * NPB;
                    const int hp = l / WPDIM;
                    const int wp = l - hp * WPDIM;
                    const int c  = col >> 8, ph = (col >> 4) & 15, pw = col & 15;
                    const size_t idx = ((size_t)(b * 3 + c) * 384 + hp * 16 + ph) * 384 + wp * 16 + pw;
                    out[idx] = xres[idx] + v;
                }
            }
        }
    }
}

// ---------------------------------------------------------------------------
extern "C" void kernel_launch(void* const* d_in, const int* in_sizes, int n_in,
                              void* d_out, int out_size, void* d_ws, size_t ws_size,
                              hipStream_t stream)
{
    const float* x   = (const float*)d_in[0];
    const float* lnw = (const float*)d_in[1];
    const float* lnb = (const float*)d_in[2];
    const float* w1  = (const float*)d_in[3];
    const float* b1  = (const float*)d_in[4];
    const float* w2  = (const float*)d_in[5];
    const float* b2  = (const float*)d_in[6];
    float* out = (float*)d_out;

    char* ws = (char*)d_ws;
    size_t o = 0;
    ushort* Yhi  = (ushort*)(ws + o); o += (size_t)TOK * PS * 2;
    ushort* Ylo  = (ushort*)(ws + o); o += (size_t)TOK * PS * 2;
    ushort* W1h  = (ushort*)(ws + o); o += (size_t)PS * HID * 2;
    ushort* W1l  = (ushort*)(ws + o); o += (size_t)PS * HID * 2;
    ushort* W2h  = (ushort*)(ws + o); o += (size_t)HID * PS * 2;
    ushort* W2l  = (ushort*)(ws + o); o += (size_t)HID * PS * 2;
    ushort* Hh   = (ushort*)(ws + o); o += (size_t)TOK * HID * 2;
    ushort* Hl   = (ushort*)(ws + o); o += (size_t)TOK * HID * 2;

    wsplit_transpose<<<dim3(HID / 32, PS / 32), 256, 0, stream>>>(w1, PS, HID, W1h, W1l);
    wsplit_transpose<<<dim3(PS / 32, HID / 32), 256, 0, stream>>>(w2, HID, PS, W2h, W2l);

    patch_ln_kernel<<<TOK / 4, 256, 0, stream>>>(x, lnw, lnb, Yhi, Ylo);

    // GEMM1: [TOK,PS] x [PS,HID] -> H, +b1, GELU, split.  grid 6*144=864 (%8==0)
    gemm_bf16x3_8p<1><<<(HID / 256) * (TOK / 256), 512, 0, stream>>>(
        Yhi, Ylo, W1h, W1l, b1, TOK, HID, PS, HID / 256, Hh, Hl, nullptr, nullptr);

    // GEMM2: [TOK,HID] x [HID,PS] -> fold + residual.  grid 3*144=432 (%8==0)
    gemm_bf16x3_8p<0><<<(PS / 256) * (TOK / 256), 512, 0, stream>>>(
        Hh, Hl, W2h, W2l, b2, TOK, PS, HID, PS / 256, nullptr, nullptr, x, out);
}